// Round 1
// baseline (45.764 us; speedup 1.0000x reference)
//
#include <hip/hip_runtime.h>
#include <math.h>

#ifndef M_PI
#define M_PI 3.14159265358979323846
#endif

constexpr int T_LEN = 4096;
constexpr int KMIN = 41;
constexpr int KMAX = 2047;
constexpr float NK_F = 2007.0f;

__device__ __forceinline__ void sincos_rev(float rev, float& s, float& c) {
    // hardware v_sin/v_cos take REVOLUTIONS; rev is exact (m / 2^n)
    s = __builtin_amdgcn_sinf(rev);
    c = __builtin_amdgcn_cosf(rev);
}

// One block per batch row. alpha[b] via 2-stage DFT (4096 = 64 x 64)
// + f32 log-log spectral regression, matching the reference pipeline.
__global__ __launch_bounds__(256) void alpha_kernel(const float* __restrict__ x,
                                                    float* __restrict__ alpha_out) {
    const int b = blockIdx.x;
    const int tid = threadIdx.x;

    __shared__ float xs[T_LEN];
    __shared__ float2 As[64 * 64];   // As[b2][r]
    __shared__ float rbuf[8];

    const float* xr = x + (size_t)b * T_LEN;
    for (int i = tid; i < T_LEN; i += 256) xs[i] = xr[i];
    __syncthreads();

    // Phase A: A[r, b2] = sum_a x[64a + b2] * e^{-2pi i r a / 64}
    // wave: b2 uniform (xs read broadcasts), r = lane (conflict-free As write)
    for (int i = 0; i < 16; ++i) {
        int p = tid + 256 * i;
        int b2 = p >> 6;
        int r  = p & 63;
        float re = 0.f, im = 0.f;
        int m = 0;
        for (int a = 0; a < 64; ++a) {
            float s, c;
            sincos_rev((float)m * (1.0f / 64.0f), s, c);
            float xv = xs[(a << 6) + b2];
            re = fmaf(xv, c, re);
            im = fmaf(xv, -s, im);
            m = (m + r) & 63;
        }
        As[(b2 << 6) + r] = make_float2(re, im);
    }
    __syncthreads();

    // Phase B: X[k] = sum_b2 A[k&63, b2] * e^{-2pi i k b2 / 4096}
    // lanes have consecutive k -> consecutive r -> conflict-free As reads
    float lk_arr[8], lp_arr[8];
    float sum_lk = 0.f, sum_lp = 0.f;
#pragma unroll
    for (int i = 0; i < 8; ++i) {
        int k = KMIN + tid + 256 * i;
        lk_arr[i] = 0.f; lp_arr[i] = 0.f;
        if (k <= KMAX) {
            int r = k & 63;
            float xre = 0.f, xim = 0.f;
            int m = 0;
            for (int bb = 0; bb < 64; ++bb) {
                float s, c;
                sincos_rev((float)m * (1.0f / 4096.0f), s, c);
                float2 A = As[(bb << 6) + r];
                xre = fmaf(A.x, c, fmaf(A.y,  s, xre));
                xim = fmaf(A.y, c, fmaf(-A.x, s, xim));
                m = (m + k) & 4095;
            }
            float power = xre * xre + xim * xim;
            float lp = logf(power + 1e-10f);
            float lk = logf((float)k * (1.0f / 4096.0f) + 1e-10f);
            lk_arr[i] = lk; lp_arr[i] = lp;
            sum_lk += lk; sum_lp += lp;
        }
    }

    // block-reduce (sum_lk, sum_lp) -> means over exactly 2007 bins
    float a1 = sum_lk, a2 = sum_lp;
    for (int off = 32; off > 0; off >>= 1) {
        a1 += __shfl_down(a1, off, 64);
        a2 += __shfl_down(a2, off, 64);
    }
    const int wid = tid >> 6, lane = tid & 63;
    if (lane == 0) { rbuf[wid] = a1; rbuf[4 + wid] = a2; }
    __syncthreads();
    const float mean_lk = (rbuf[0] + rbuf[1] + rbuf[2] + rbuf[3]) * (1.0f / NK_F);
    const float mean_lp = (rbuf[4] + rbuf[5] + rbuf[6] + rbuf[7]) * (1.0f / NK_F);
    __syncthreads();

    float cov = 0.f, var = 0.f;
#pragma unroll
    for (int i = 0; i < 8; ++i) {
        int k = KMIN + tid + 256 * i;
        if (k <= KMAX) {
            float lkc = lk_arr[i] - mean_lk;
            float lpc = lp_arr[i] - mean_lp;
            cov = fmaf(lkc, lpc, cov);
            var = fmaf(lkc, lkc, var);
        }
    }
    float c1 = cov, c2 = var;
    for (int off = 32; off > 0; off >>= 1) {
        c1 += __shfl_down(c1, off, 64);
        c2 += __shfl_down(c2, off, 64);
    }
    if (lane == 0) { rbuf[wid] = c1; rbuf[4 + wid] = c2; }
    __syncthreads();
    if (tid == 0) {
        float covT = rbuf[0] + rbuf[1] + rbuf[2] + rbuf[3];
        float varT = rbuf[4] + rbuf[5] + rbuf[6] + rbuf[7];
        float beta = -covT / (varT + 1e-10f);
        float D = (3.0f - beta) * 0.5f;
        D = fminf(fmaxf(D, 0.5f), 1.5f);
        float al = 1.0f + 0.8f * (D - 1.0f);
        al = fminf(fmaxf(al, 0.1f), 3.0f);
        alpha_out[b] = al;
    }
}

// logits[b, v] = 10*|amp*(cos(ph)*psi0 + sin(ph)*psi1)| / (|amp| + 1e-8)
__global__ __launch_bounds__(256) void logits_kernel(const float* __restrict__ psi,
                                                     const float* __restrict__ alpha,
                                                     float* __restrict__ out) {
    const int b = blockIdx.y;
    const int j = blockIdx.x * 256 + threadIdx.x;   // [0, 32000) float4 index
    const float al = alpha[b];
    const float p0 = psi[b * 4 + 0];
    const float p1 = psi[b * 4 + 1];

    const float OMEGA = (float)(2.0 * M_PI);
    const float KWAVE = (float)(2.0 * M_PI / 0.5);

    float tmp[4];
#pragma unroll
    for (int u = 0; u < 4; ++u) {
        int v = j * 4 + u;
        float lam = (float)v / 128000.0f;
        float amp = sinf(OMEGA + al * lam);
        float ph  = OMEGA - KWAVE * lam + 0.01f * (lam * lam);
        float s = sinf(ph);
        float c = cosf(ph);
        float coup = (amp * c * p0 + amp * s * p1) / (fabsf(amp) + 1e-8f);
        tmp[u] = 10.0f * fabsf(coup);
    }
    float4 res;
    res.x = tmp[0]; res.y = tmp[1]; res.z = tmp[2]; res.w = tmp[3];
    reinterpret_cast<float4*>(out)[(size_t)b * 32000 + j] = res;
}

extern "C" void kernel_launch(void* const* d_in, const int* in_sizes, int n_in,
                              void* d_out, int out_size, void* d_ws, size_t ws_size,
                              hipStream_t stream) {
    const float* x   = (const float*)d_in[0];   // [32, 4096] f32
    const float* psi = (const float*)d_in[1];   // [32, 4] f32
    float* out   = (float*)d_out;               // [32, 128000] f32
    float* alpha = (float*)d_ws;                // 32 floats scratch

    alpha_kernel<<<32, 256, 0, stream>>>(x, alpha);
    logits_kernel<<<dim3(125, 32), 256, 0, stream>>>(psi, alpha, out);
}